// Round 1
// baseline (203.659 us; speedup 1.0000x reference)
//
#include <hip/hip_runtime.h>

#define Bc 2
#define Tc 384
#define Ec 768
#define Hc 12
#define HDc 64
#define TTc 16          // t-rows per attention block
#define SCc 64          // s-chunk staged in LDS
#define NCHUNK (Tc / SCc)

__device__ __forceinline__ float fexp2(float x) {
#if __has_builtin(__builtin_amdgcn_exp2f)
    return __builtin_amdgcn_exp2f(x);
#else
    return exp2f(x);
#endif
}

__device__ __forceinline__ float frcp(float x) {
#if __has_builtin(__builtin_amdgcn_rcpf)
    return __builtin_amdgcn_rcpf(x);
#else
    return 1.0f / x;
#endif
}

// tanh(x) = (e^{2x}-1)/(e^{2x}+1); e^{2x} = 2^{x*2*log2(e)}
__device__ __forceinline__ float ftanh(float x) {
    float e = fexp2(x * 2.8853900817779268f);
    return (e - 1.0f) * frcp(e + 1.0f);
}

// C[z] = A @ W[z] + b[z]; all matrices row-major, M=768 (B*T), N=K=768 (E).
// 64x64 tile per block, 256 threads, 4x4 micro-tile per thread, K-step 16.
__global__ __launch_bounds__(256) void gemm3(
    const float* __restrict__ A,
    const float* __restrict__ W0, const float* __restrict__ W1, const float* __restrict__ W2,
    const float* __restrict__ b0, const float* __restrict__ b1, const float* __restrict__ b2,
    float* __restrict__ C0, float* __restrict__ C1, float* __restrict__ C2)
{
    const int K = Ec, N = Ec;
    const int z = blockIdx.z;
    const float* W    = (z == 0) ? W0 : (z == 1) ? W1 : W2;
    const float* bias = (z == 0) ? b0 : (z == 1) ? b1 : b2;
    float*       C    = (z == 0) ? C0 : (z == 1) ? C1 : C2;

    __shared__ float As[16][65];  // [k][m], padded
    __shared__ float Bs[16][64];  // [k][n]

    const int tid = threadIdx.x;
    const int tx = tid & 15, ty = tid >> 4;
    const int m0 = blockIdx.y * 64, n0 = blockIdx.x * 64;
    const int ar = tid >> 2, ak = (tid & 3) << 2;   // A: row 0..63, 4 consecutive k
    const int br = tid >> 4, bn = (tid & 15) << 2;  // B: k 0..15, 4 consecutive n

    float acc[4][4] = {};

    for (int k0 = 0; k0 < K; k0 += 16) {
        float4 av = *reinterpret_cast<const float4*>(&A[(m0 + ar) * K + k0 + ak]);
        float4 bv = *reinterpret_cast<const float4*>(&W[(k0 + br) * N + n0 + bn]);
        As[ak + 0][ar] = av.x;
        As[ak + 1][ar] = av.y;
        As[ak + 2][ar] = av.z;
        As[ak + 3][ar] = av.w;
        *reinterpret_cast<float4*>(&Bs[br][bn]) = bv;
        __syncthreads();
#pragma unroll
        for (int kk = 0; kk < 16; ++kk) {
            float a0 = As[kk][ty * 4 + 0];
            float a1 = As[kk][ty * 4 + 1];
            float a2 = As[kk][ty * 4 + 2];
            float a3 = As[kk][ty * 4 + 3];
            float4 b4 = *reinterpret_cast<const float4*>(&Bs[kk][tx * 4]);
            acc[0][0] = fmaf(a0, b4.x, acc[0][0]); acc[0][1] = fmaf(a0, b4.y, acc[0][1]);
            acc[0][2] = fmaf(a0, b4.z, acc[0][2]); acc[0][3] = fmaf(a0, b4.w, acc[0][3]);
            acc[1][0] = fmaf(a1, b4.x, acc[1][0]); acc[1][1] = fmaf(a1, b4.y, acc[1][1]);
            acc[1][2] = fmaf(a1, b4.z, acc[1][2]); acc[1][3] = fmaf(a1, b4.w, acc[1][3]);
            acc[2][0] = fmaf(a2, b4.x, acc[2][0]); acc[2][1] = fmaf(a2, b4.y, acc[2][1]);
            acc[2][2] = fmaf(a2, b4.z, acc[2][2]); acc[2][3] = fmaf(a2, b4.w, acc[2][3]);
            acc[3][0] = fmaf(a3, b4.x, acc[3][0]); acc[3][1] = fmaf(a3, b4.y, acc[3][1]);
            acc[3][2] = fmaf(a3, b4.z, acc[3][2]); acc[3][3] = fmaf(a3, b4.w, acc[3][3]);
        }
        __syncthreads();
    }

#pragma unroll
    for (int i = 0; i < 4; ++i) {
        int m = m0 + ty * 4 + i;
#pragma unroll
        for (int j = 0; j < 4; ++j) {
            int n = n0 + tx * 4 + j;
            C[m * N + n] = acc[i][j] + bias[n];
        }
    }
}

// One block per (b*h, 16-t tile); 256 threads = 4 waves.
// Phase 1: scores via lane-per-s (K chunk staged transposed in LDS).
// Phase 2: softmax per t (wave-butterfly over 64 lanes, 6 values each).
// Phase 3: PV with V chunks staged in LDS; lane-per-d.
__global__ __launch_bounds__(256) void attn_kernel(
    const float* __restrict__ Q, const float* __restrict__ Km, const float* __restrict__ V,
    const float* __restrict__ w_score, const float* __restrict__ b_score,
    float* __restrict__ O)
{
    const int bh = blockIdx.x;          // 0..23
    const int b = bh / Hc, h = bh % Hc;
    const int t0 = blockIdx.y * TTc;
    const int tid = threadIdx.x;
    const int wave = tid >> 6, lane = tid & 63;

    __shared__ float qs[TTc][HDc];            // 4 KB
    __shared__ float kv[HDc * (SCc + 1)];     // 16.25 KB: kT[d][s] (phase1) / vs[s][d] (phase3)
    __shared__ float sc[TTc][Tc];             // 24 KB: scores -> unnormalized probs
    __shared__ float wsh[HDc];
    __shared__ float rinvs[TTc];

    // ---- phase 0: load Q tile + w_score ----
    {
        int tr = tid >> 4, d4 = (tid & 15) << 2;
        float4 qv = *reinterpret_cast<const float4*>(&Q[(b * Tc + t0 + tr) * Ec + h * HDc + d4]);
        *reinterpret_cast<float4*>(&qs[tr][d4]) = qv;
        if (tid < HDc) wsh[tid] = w_score[tid];
    }
    const float bsc = b_score[0];
    __syncthreads();

    const int ta = wave, tb = wave + 4, tcc = wave + 8, td = wave + 12;

    // ---- phase 1: scores ----
    for (int c = 0; c < NCHUNK; ++c) {
        const int s0 = c * SCc;
        // stage K chunk transposed: kT[d][s] = K[s][d], stride SCc+1
#pragma unroll
        for (int i = 0; i < 4; ++i) {
            int id = i * 256 + tid;
            int sr = id >> 4, d4 = (id & 15) << 2;
            float4 kvv = *reinterpret_cast<const float4*>(
                &Km[(b * Tc + s0 + sr) * Ec + h * HDc + d4]);
            kv[(d4 + 0) * (SCc + 1) + sr] = kvv.x;
            kv[(d4 + 1) * (SCc + 1) + sr] = kvv.y;
            kv[(d4 + 2) * (SCc + 1) + sr] = kvv.z;
            kv[(d4 + 3) * (SCc + 1) + sr] = kvv.w;
        }
        __syncthreads();
        float acc0 = 0.f, acc1 = 0.f, acc2 = 0.f, acc3 = 0.f;
#pragma unroll 4
        for (int d = 0; d < HDc; ++d) {
            float kval = kv[d * (SCc + 1) + lane];
            float wv = wsh[d];
            acc0 = fmaf(ftanh(qs[ta][d] + kval), wv, acc0);
            acc1 = fmaf(ftanh(qs[tb][d] + kval), wv, acc1);
            acc2 = fmaf(ftanh(qs[tcc][d] + kval), wv, acc2);
            acc3 = fmaf(ftanh(qs[td][d] + kval), wv, acc3);
        }
        sc[ta][s0 + lane] = acc0 + bsc;
        sc[tb][s0 + lane] = acc1 + bsc;
        sc[tcc][s0 + lane] = acc2 + bsc;
        sc[td][s0 + lane] = acc3 + bsc;
        __syncthreads();
    }

    // ---- phase 2: softmax over s for each t (one wave handles 4 t's) ----
#pragma unroll
    for (int j = 0; j < 4; ++j) {
        int t = wave + 4 * j;
        float vals[NCHUNK];
        float m = -1e30f;
#pragma unroll
        for (int cC = 0; cC < NCHUNK; ++cC) {
            vals[cC] = sc[t][lane + 64 * cC];
            m = fmaxf(m, vals[cC]);
        }
#pragma unroll
        for (int off = 32; off > 0; off >>= 1) m = fmaxf(m, __shfl_xor(m, off, 64));
        float sum = 0.f;
#pragma unroll
        for (int cC = 0; cC < NCHUNK; ++cC) {
            float p = fexp2((vals[cC] - m) * 1.4426950408889634f);
            sc[t][lane + 64 * cC] = p;
            sum += p;
        }
#pragma unroll
        for (int off = 32; off > 0; off >>= 1) sum += __shfl_xor(sum, off, 64);
        if (lane == 0) rinvs[t] = frcp(sum);
    }
    __syncthreads();

    // ---- phase 3: PV ----
    float o0 = 0.f, o1 = 0.f, o2 = 0.f, o3 = 0.f;
    for (int c = 0; c < NCHUNK; ++c) {
        const int s0 = c * SCc;
        // stage V chunk natural layout vs[s][d]
#pragma unroll
        for (int i = 0; i < 4; ++i) {
            int id = i * 256 + tid;
            int sr = id >> 4, d4 = (id & 15) << 2;
            float4 vv = *reinterpret_cast<const float4*>(
                &V[(b * Tc + s0 + sr) * Ec + h * HDc + d4]);
            *reinterpret_cast<float4*>(&kv[sr * HDc + d4]) = vv;
        }
        __syncthreads();
#pragma unroll 8
        for (int s = 0; s < SCc; ++s) {
            float vvv = kv[s * HDc + lane];
            o0 = fmaf(sc[ta][s0 + s], vvv, o0);
            o1 = fmaf(sc[tb][s0 + s], vvv, o1);
            o2 = fmaf(sc[tcc][s0 + s], vvv, o2);
            o3 = fmaf(sc[td][s0 + s], vvv, o3);
        }
        __syncthreads();
    }
    O[(b * Tc + t0 + ta)  * Ec + h * HDc + lane] = o0 * rinvs[ta];
    O[(b * Tc + t0 + tb)  * Ec + h * HDc + lane] = o1 * rinvs[tb];
    O[(b * Tc + t0 + tcc) * Ec + h * HDc + lane] = o2 * rinvs[tcc];
    O[(b * Tc + t0 + td)  * Ec + h * HDc + lane] = o3 * rinvs[td];
}

extern "C" void kernel_launch(void* const* d_in, const int* in_sizes, int n_in,
                              void* d_out, int out_size, void* d_ws, size_t ws_size,
                              hipStream_t stream) {
    const float* hs  = (const float*)d_in[0];
    const float* Wq  = (const float*)d_in[1];
    const float* bq  = (const float*)d_in[2];
    const float* Wk  = (const float*)d_in[3];
    const float* bk  = (const float*)d_in[4];
    const float* Wv  = (const float*)d_in[5];
    const float* bv  = (const float*)d_in[6];
    const float* Wo  = (const float*)d_in[7];
    const float* bo  = (const float*)d_in[8];
    const float* wsc = (const float*)d_in[9];
    const float* bsc = (const float*)d_in[10];
    float* out = (float*)d_out;
    float* wsp = (float*)d_ws;

    const size_t MAT = (size_t)(Bc * Tc) * Ec;  // 589824 floats per matrix
    float* Qw  = wsp;
    float* Kw  = wsp + MAT;
    float* Vw  = wsp + 2 * MAT;
    float* ATT = wsp + 3 * MAT;

    // QKV projections: one launch, z picks {Wq,Wk,Wv}
    gemm3<<<dim3(Ec / 64, (Bc * Tc) / 64, 3), 256, 0, stream>>>(
        hs, Wq, Wk, Wv, bq, bk, bv, Qw, Kw, Vw);

    // additive attention
    attn_kernel<<<dim3(Bc * Hc, Tc / TTc), 256, 0, stream>>>(Qw, Kw, Vw, wsc, bsc, ATT);

    // output projection
    gemm3<<<dim3(Ec / 64, (Bc * Tc) / 64, 1), 256, 0, stream>>>(
        ATT, Wo, Wo, Wo, bo, bo, bo, out, out, out);
}

// Round 2
// 135.718 us; speedup vs baseline: 1.5006x; 1.5006x over previous
//
#include <hip/hip_runtime.h>

#define Bc 2
#define Tc 384
#define Ec 768
#define Hc 12
#define HDc 64
#define TTc 16          // t-rows per attention block
#define SCc 64          // s-chunk staged in LDS
#define NCHUNK (Tc / SCc)

typedef __attribute__((ext_vector_type(8))) short short8;
typedef __attribute__((ext_vector_type(4))) float f32x4;

__device__ __forceinline__ float fexp2(float x) { return __builtin_amdgcn_exp2f(x); }
__device__ __forceinline__ float frcp(float x)  { return __builtin_amdgcn_rcpf(x); }

__device__ __forceinline__ unsigned short bf16_rne(float x) {
    unsigned u = __float_as_uint(x);
    u += 0x7fffu + ((u >> 16) & 1u);
    return (unsigned short)(u >> 16);
}
__device__ __forceinline__ float bf16_to_f(unsigned short h) {
    return __uint_as_float(((unsigned)h) << 16);
}

// ---------------------------------------------------------------------------
// prep: split hs -> bf16 hi/lo; transpose+split Wq/Wk/Wv/Wo -> WT hi/lo [n][k]
// grid.x = 144 (hs split) + 4*144 (weight transpose tiles) = 720 blocks
// ---------------------------------------------------------------------------
__global__ __launch_bounds__(256) void prep_kernel(
    const float* __restrict__ hs,
    const float* __restrict__ Wq, const float* __restrict__ Wk,
    const float* __restrict__ Wv, const float* __restrict__ Wo,
    unsigned short* __restrict__ hs_hi, unsigned short* __restrict__ hs_lo,
    unsigned short* __restrict__ wt_hi, unsigned short* __restrict__ wt_lo)
{
    const int tid = threadIdx.x;
    int id = blockIdx.x;
    if (id < 144) {
        // split hs: 589824 elems, 4096 per block, 16 per thread
        int base = id * 4096 + tid * 16;
#pragma unroll
        for (int i = 0; i < 4; ++i) {
            float4 x = *reinterpret_cast<const float4*>(&hs[base + i * 4]);
            ushort4 hv, lv;
            hv.x = bf16_rne(x.x); lv.x = bf16_rne(x.x - bf16_to_f(hv.x));
            hv.y = bf16_rne(x.y); lv.y = bf16_rne(x.y - bf16_to_f(hv.y));
            hv.z = bf16_rne(x.z); lv.z = bf16_rne(x.z - bf16_to_f(hv.z));
            hv.w = bf16_rne(x.w); lv.w = bf16_rne(x.w - bf16_to_f(hv.w));
            *reinterpret_cast<ushort4*>(&hs_hi[base + i * 4]) = hv;
            *reinterpret_cast<ushort4*>(&hs_lo[base + i * 4]) = lv;
        }
    } else {
        id -= 144;
        const int w = id / 144, t = id % 144;
        const int tr = t / 12, tc2 = t % 12;  // tile row (k), tile col (n)
        const float* W = (w == 0) ? Wq : (w == 1) ? Wk : (w == 2) ? Wv : Wo;
        unsigned short* TH = wt_hi + (size_t)w * Ec * Ec;
        unsigned short* TL = wt_lo + (size_t)w * Ec * Ec;

        __shared__ float tile[64][68];  // [k][n], pad 68 keeps rows 16B-aligned
        const int r = tid >> 2, c0 = (tid & 3) * 16;
#pragma unroll
        for (int i = 0; i < 4; ++i)
            *reinterpret_cast<float4*>(&tile[r][c0 + i * 4]) =
                *reinterpret_cast<const float4*>(&W[(tr * 64 + r) * Ec + tc2 * 64 + c0 + i * 4]);
        __syncthreads();
        const int n = tid >> 2, k0 = (tid & 3) * 4;
#pragma unroll
        for (int i = 0; i < 4; ++i) {
            int k = k0 + i * 16;
            float v0 = tile[k + 0][n], v1 = tile[k + 1][n];
            float v2 = tile[k + 2][n], v3 = tile[k + 3][n];
            ushort4 hv, lv;
            hv.x = bf16_rne(v0); lv.x = bf16_rne(v0 - bf16_to_f(hv.x));
            hv.y = bf16_rne(v1); lv.y = bf16_rne(v1 - bf16_to_f(hv.y));
            hv.z = bf16_rne(v2); lv.z = bf16_rne(v2 - bf16_to_f(hv.z));
            hv.w = bf16_rne(v3); lv.w = bf16_rne(v3 - bf16_to_f(hv.w));
            size_t off = (size_t)(tc2 * 64 + n) * Ec + tr * 64 + k;
            *reinterpret_cast<ushort4*>(&TH[off]) = hv;
            *reinterpret_cast<ushort4*>(&TL[off]) = lv;
        }
    }
}

// ---------------------------------------------------------------------------
// Split-bf16 MFMA GEMM: C[z] = A @ W[z] + b[z]  (fp32-grade via 3 products)
// A given as hi/lo bf16 [768][768]; W given pre-transposed WT[n][k] hi/lo.
// 64x64 tile, 256 thr = 4 waves of 32x32, BK=64, mfma_f32_16x16x32_bf16.
// ---------------------------------------------------------------------------
__global__ __launch_bounds__(256) void gemm_mfma(
    const unsigned short* __restrict__ Ahi, const unsigned short* __restrict__ Alo,
    const unsigned short* __restrict__ Bh0, const unsigned short* __restrict__ Bl0,
    const unsigned short* __restrict__ Bh1, const unsigned short* __restrict__ Bl1,
    const unsigned short* __restrict__ Bh2, const unsigned short* __restrict__ Bl2,
    const float* __restrict__ b0, const float* __restrict__ b1, const float* __restrict__ b2,
    float* __restrict__ C0, float* __restrict__ C1, float* __restrict__ C2)
{
    const int z = blockIdx.z;
    const unsigned short* Bhi = (z == 0) ? Bh0 : (z == 1) ? Bh1 : Bh2;
    const unsigned short* Blo = (z == 0) ? Bl0 : (z == 1) ? Bl1 : Bl2;
    const float* bias = (z == 0) ? b0 : (z == 1) ? b1 : b2;
    float* C = (z == 0) ? C0 : (z == 1) ? C1 : C2;

    __shared__ __align__(16) short sAh[64][72], sAl[64][72], sBh[64][72], sBl[64][72];

    const int tid = threadIdx.x;
    const int m0 = blockIdx.y * 64, n0 = blockIdx.x * 64;
    const int wave = tid >> 6, lane = tid & 63;
    const int wm = (wave >> 1) * 32, wn = (wave & 1) * 32;
    const int fr = lane & 15, fk = (lane >> 4) * 8;
    const int sr = tid >> 3, sg = (tid & 7) * 8;  // staging: row, granule*8

    f32x4 zero = {0.f, 0.f, 0.f, 0.f};
    f32x4 acc[2][2];
    acc[0][0] = zero; acc[0][1] = zero; acc[1][0] = zero; acc[1][1] = zero;

    for (int kc = 0; kc < Ec; kc += 64) {
        int4 a0 = *reinterpret_cast<const int4*>(&Ahi[(size_t)(m0 + sr) * Ec + kc + sg]);
        int4 a1 = *reinterpret_cast<const int4*>(&Ahi[(size_t)(m0 + sr + 32) * Ec + kc + sg]);
        int4 a2 = *reinterpret_cast<const int4*>(&Alo[(size_t)(m0 + sr) * Ec + kc + sg]);
        int4 a3 = *reinterpret_cast<const int4*>(&Alo[(size_t)(m0 + sr + 32) * Ec + kc + sg]);
        int4 w0 = *reinterpret_cast<const int4*>(&Bhi[(size_t)(n0 + sr) * Ec + kc + sg]);
        int4 w1 = *reinterpret_cast<const int4*>(&Bhi[(size_t)(n0 + sr + 32) * Ec + kc + sg]);
        int4 w2 = *reinterpret_cast<const int4*>(&Blo[(size_t)(n0 + sr) * Ec + kc + sg]);
        int4 w3 = *reinterpret_cast<const int4*>(&Blo[(size_t)(n0 + sr + 32) * Ec + kc + sg]);
        __syncthreads();  // previous iteration's fragment reads done
        *reinterpret_cast<int4*>(&sAh[sr][sg])      = a0;
        *reinterpret_cast<int4*>(&sAh[sr + 32][sg]) = a1;
        *reinterpret_cast<int4*>(&sAl[sr][sg])      = a2;
        *reinterpret_cast<int4*>(&sAl[sr + 32][sg]) = a3;
        *reinterpret_cast<int4*>(&sBh[sr][sg])      = w0;
        *reinterpret_cast<int4*>(&sBh[sr + 32][sg]) = w1;
        *reinterpret_cast<int4*>(&sBl[sr][sg])      = w2;
        *reinterpret_cast<int4*>(&sBl[sr + 32][sg]) = w3;
        __syncthreads();

#pragma unroll
        for (int ks = 0; ks < 64; ks += 32) {
            short8 ah[2], al[2], bh[2], bl[2];
#pragma unroll
            for (int mi = 0; mi < 2; ++mi) {
                ah[mi] = *reinterpret_cast<const short8*>(&sAh[wm + mi * 16 + fr][ks + fk]);
                al[mi] = *reinterpret_cast<const short8*>(&sAl[wm + mi * 16 + fr][ks + fk]);
            }
#pragma unroll
            for (int ni = 0; ni < 2; ++ni) {
                bh[ni] = *reinterpret_cast<const short8*>(&sBh[wn + ni * 16 + fr][ks + fk]);
                bl[ni] = *reinterpret_cast<const short8*>(&sBl[wn + ni * 16 + fr][ks + fk]);
            }
#pragma unroll
            for (int mi = 0; mi < 2; ++mi)
#pragma unroll
                for (int ni = 0; ni < 2; ++ni) {
                    acc[mi][ni] = __builtin_amdgcn_mfma_f32_16x16x32_bf16(ah[mi], bh[ni], acc[mi][ni], 0, 0, 0);
                    acc[mi][ni] = __builtin_amdgcn_mfma_f32_16x16x32_bf16(ah[mi], bl[ni], acc[mi][ni], 0, 0, 0);
                    acc[mi][ni] = __builtin_amdgcn_mfma_f32_16x16x32_bf16(al[mi], bh[ni], acc[mi][ni], 0, 0, 0);
                }
        }
        __syncthreads();
    }

    const int rbase = (lane >> 4) * 4;
#pragma unroll
    for (int ni = 0; ni < 2; ++ni) {
        float bsv = bias[n0 + wn + ni * 16 + fr];
#pragma unroll
        for (int mi = 0; mi < 2; ++mi)
#pragma unroll
            for (int rr = 0; rr < 4; ++rr) {
                int row = m0 + wm + mi * 16 + rbase + rr;
                C[(size_t)row * Ec + n0 + wn + ni * 16 + fr] = acc[mi][ni][rr] + bsv;
            }
    }
}

// ---------------------------------------------------------------------------
// Additive attention. score = const - 2*S, S = sum_d w_d * rcp(1+exp2(c(q+k)))
// (constants drop out of softmax; c = 2*log2(e) folded into staged q,k).
// Emits ATT as bf16 hi/lo for the Wo MFMA GEMM.
// ---------------------------------------------------------------------------
__global__ __launch_bounds__(256) void attn_kernel(
    const float* __restrict__ Q, const float* __restrict__ Km, const float* __restrict__ V,
    const float* __restrict__ w_score,
    unsigned short* __restrict__ Ohi, unsigned short* __restrict__ Olo)
{
    const int bh = blockIdx.x;          // 0..23
    const int b = bh / Hc, h = bh % Hc;
    const int t0 = blockIdx.y * TTc;
    const int tid = threadIdx.x;
    const int wave = tid >> 6, lane = tid & 63;
    const float cc = 2.8853900817779268f;  // 2*log2(e)

    __shared__ float qs[TTc][HDc];
    __shared__ float kv[HDc * (SCc + 1)];
    __shared__ float sc[TTc][Tc];
    __shared__ float wsh[HDc];
    __shared__ float rinvs[TTc];

    {
        int tr = tid >> 4, d4 = (tid & 15) << 2;
        float4 qv = *reinterpret_cast<const float4*>(&Q[(b * Tc + t0 + tr) * Ec + h * HDc + d4]);
        qv.x *= cc; qv.y *= cc; qv.z *= cc; qv.w *= cc;
        *reinterpret_cast<float4*>(&qs[tr][d4]) = qv;
        if (tid < HDc) wsh[tid] = w_score[tid];
    }
    __syncthreads();

    const int ta = wave, tb = wave + 4, tcx = wave + 8, td = wave + 12;

    // ---- phase 1: S accumulation ----
    for (int c = 0; c < NCHUNK; ++c) {
        const int s0 = c * SCc;
#pragma unroll
        for (int i = 0; i < 4; ++i) {
            int id = i * 256 + tid;
            int srr = id >> 4, d4 = (id & 15) << 2;
            float4 kvv = *reinterpret_cast<const float4*>(
                &Km[(b * Tc + s0 + srr) * Ec + h * HDc + d4]);
            kv[(d4 + 0) * (SCc + 1) + srr] = kvv.x * cc;
            kv[(d4 + 1) * (SCc + 1) + srr] = kvv.y * cc;
            kv[(d4 + 2) * (SCc + 1) + srr] = kvv.z * cc;
            kv[(d4 + 3) * (SCc + 1) + srr] = kvv.w * cc;
        }
        __syncthreads();
        float acc0 = 0.f, acc1 = 0.f, acc2 = 0.f, acc3 = 0.f;
#pragma unroll
        for (int d4 = 0; d4 < HDc; d4 += 4) {
            float4 w4 = *reinterpret_cast<const float4*>(&wsh[d4]);
            float4 qa = *reinterpret_cast<const float4*>(&qs[ta][d4]);
            float4 qb = *reinterpret_cast<const float4*>(&qs[tb][d4]);
            float4 qc = *reinterpret_cast<const float4*>(&qs[tcx][d4]);
            float4 qd = *reinterpret_cast<const float4*>(&qs[td][d4]);
            float k0 = kv[(d4 + 0) * (SCc + 1) + lane];
            float k1 = kv[(d4 + 1) * (SCc + 1) + lane];
            float k2 = kv[(d4 + 2) * (SCc + 1) + lane];
            float k3 = kv[(d4 + 3) * (SCc + 1) + lane];
            acc0 = fmaf(w4.x, frcp(1.f + fexp2(qa.x + k0)), acc0);
            acc0 = fmaf(w4.y, frcp(1.f + fexp2(qa.y + k1)), acc0);
            acc0 = fmaf(w4.z, frcp(1.f + fexp2(qa.z + k2)), acc0);
            acc0 = fmaf(w4.w, frcp(1.f + fexp2(qa.w + k3)), acc0);
            acc1 = fmaf(w4.x, frcp(1.f + fexp2(qb.x + k0)), acc1);
            acc1 = fmaf(w4.y, frcp(1.f + fexp2(qb.y + k1)), acc1);
            acc1 = fmaf(w4.z, frcp(1.f + fexp2(qb.z + k2)), acc1);
            acc1 = fmaf(w4.w, frcp(1.f + fexp2(qb.w + k3)), acc1);
            acc2 = fmaf(w4.x, frcp(1.f + fexp2(qc.x + k0)), acc2);
            acc2 = fmaf(w4.y, frcp(1.f + fexp2(qc.y + k1)), acc2);
            acc2 = fmaf(w4.z, frcp(1.f + fexp2(qc.z + k2)), acc2);
            acc2 = fmaf(w4.w, frcp(1.f + fexp2(qc.w + k3)), acc2);
            acc3 = fmaf(w4.x, frcp(1.f + fexp2(qd.x + k0)), acc3);
            acc3 = fmaf(w4.y, frcp(1.f + fexp2(qd.y + k1)), acc3);
            acc3 = fmaf(w4.z, frcp(1.f + fexp2(qd.z + k2)), acc3);
            acc3 = fmaf(w4.w, frcp(1.f + fexp2(qd.w + k3)), acc3);
        }
        sc[ta][s0 + lane] = acc0;
        sc[tb][s0 + lane] = acc1;
        sc[tcx][s0 + lane] = acc2;
        sc[td][s0 + lane] = acc3;
        __syncthreads();
    }

    // ---- phase 2: softmax (min over S since score = -2S) ----
#pragma unroll
    for (int j = 0; j < 4; ++j) {
        int t = wave + 4 * j;
        float vals[NCHUNK];
        float m = 1e30f;
#pragma unroll
        for (int cC = 0; cC < NCHUNK; ++cC) {
            vals[cC] = sc[t][lane + 64 * cC];
            m = fminf(m, vals[cC]);
        }
#pragma unroll
        for (int off = 32; off > 0; off >>= 1) m = fminf(m, __shfl_xor(m, off, 64));
        float sum = 0.f;
#pragma unroll
        for (int cC = 0; cC < NCHUNK; ++cC) {
            float p = fexp2((m - vals[cC]) * cc);   // exp(-2(S-m)) = 2^{(m-S)*2log2e}
            sc[t][lane + 64 * cC] = p;
            sum += p;
        }
#pragma unroll
        for (int off = 32; off > 0; off >>= 1) sum += __shfl_xor(sum, off, 64);
        if (lane == 0) rinvs[t] = frcp(sum);
    }
    __syncthreads();

    // ---- phase 3: PV ----
    float o0 = 0.f, o1 = 0.f, o2 = 0.f, o3 = 0.f;
    for (int c = 0; c < NCHUNK; ++c) {
        const int s0 = c * SCc;
#pragma unroll
        for (int i = 0; i < 4; ++i) {
            int id = i * 256 + tid;
            int srr = id >> 4, d4 = (id & 15) << 2;
            float4 vv = *reinterpret_cast<const float4*>(
                &V[(b * Tc + s0 + srr) * Ec + h * HDc + d4]);
            *reinterpret_cast<float4*>(&kv[srr * HDc + d4]) = vv;
        }
        __syncthreads();
#pragma unroll
        for (int s4 = 0; s4 < SCc; s4 += 4) {
            float4 pa = *reinterpret_cast<const float4*>(&sc[ta][s0 + s4]);
            float4 pb = *reinterpret_cast<const float4*>(&sc[tb][s0 + s4]);
            float4 pc = *reinterpret_cast<const float4*>(&sc[tcx][s0 + s4]);
            float4 pd = *reinterpret_cast<const float4*>(&sc[td][s0 + s4]);
            float v0 = kv[(s4 + 0) * HDc + lane];
            float v1 = kv[(s4 + 1) * HDc + lane];
            float v2 = kv[(s4 + 2) * HDc + lane];
            float v3 = kv[(s4 + 3) * HDc + lane];
            o0 = fmaf(pa.x, v0, o0); o0 = fmaf(pa.y, v1, o0);
            o0 = fmaf(pa.z, v2, o0); o0 = fmaf(pa.w, v3, o0);
            o1 = fmaf(pb.x, v0, o1); o1 = fmaf(pb.y, v1, o1);
            o1 = fmaf(pb.z, v2, o1); o1 = fmaf(pb.w, v3, o1);
            o2 = fmaf(pc.x, v0, o2); o2 = fmaf(pc.y, v1, o2);
            o2 = fmaf(pc.z, v2, o2); o2 = fmaf(pc.w, v3, o2);
            o3 = fmaf(pd.x, v0, o3); o3 = fmaf(pd.y, v1, o3);
            o3 = fmaf(pd.z, v2, o3); o3 = fmaf(pd.w, v3, o3);
        }
        __syncthreads();
    }

    // epilogue: normalize + split to bf16 hi/lo
    const int tlist[4] = {ta, tb, tcx, td};
    float olist[4] = {o0, o1, o2, o3};
#pragma unroll
    for (int j = 0; j < 4; ++j) {
        float x = olist[j] * rinvs[tlist[j]];
        unsigned short hb = bf16_rne(x);
        unsigned short lb = bf16_rne(x - bf16_to_f(hb));
        size_t idx = (size_t)(b * Tc + t0 + tlist[j]) * Ec + h * HDc + lane;
        Ohi[idx] = hb;
        Olo[idx] = lb;
    }
}

extern "C" void kernel_launch(void* const* d_in, const int* in_sizes, int n_in,
                              void* d_out, int out_size, void* d_ws, size_t ws_size,
                              hipStream_t stream) {
    const float* hs  = (const float*)d_in[0];
    const float* Wq  = (const float*)d_in[1];
    const float* bq  = (const float*)d_in[2];
    const float* Wk  = (const float*)d_in[3];
    const float* bk  = (const float*)d_in[4];
    const float* Wv  = (const float*)d_in[5];
    const float* bv  = (const float*)d_in[6];
    const float* Wo  = (const float*)d_in[7];
    const float* bo  = (const float*)d_in[8];
    const float* wsc = (const float*)d_in[9];
    float* out = (float*)d_out;

    const size_t MAT = (size_t)(Bc * Tc) * Ec;  // 589824
    float* Qw = (float*)d_ws;
    float* Kw = Qw + MAT;
    float* Vw = Kw + MAT;
    unsigned short* HS_HI = (unsigned short*)(Vw + MAT);
    unsigned short* HS_LO = HS_HI + MAT;         // HS_HI/LO reused as ATT hi/lo after G1
    unsigned short* WT_HI = HS_LO + MAT;         // 4 matrices, order q,k,v,o
    unsigned short* WT_LO = WT_HI + 4 * MAT;

    prep_kernel<<<720, 256, 0, stream>>>(hs, Wq, Wk, Wv, Wo, HS_HI, HS_LO, WT_HI, WT_LO);

    gemm_mfma<<<dim3(Ec / 64, (Bc * Tc) / 64, 3), 256, 0, stream>>>(
        HS_HI, HS_LO,
        WT_HI + 0 * MAT, WT_LO + 0 * MAT,
        WT_HI + 1 * MAT, WT_LO + 1 * MAT,
        WT_HI + 2 * MAT, WT_LO + 2 * MAT,
        bq, bk, bv, Qw, Kw, Vw);

    attn_kernel<<<dim3(Bc * Hc, Tc / TTc), 256, 0, stream>>>(
        Qw, Kw, Vw, wsc, HS_HI, HS_LO);   // writes ATT hi/lo over hs hi/lo

    gemm_mfma<<<dim3(Ec / 64, (Bc * Tc) / 64, 1), 256, 0, stream>>>(
        HS_HI, HS_LO,
        WT_HI + 3 * MAT, WT_LO + 3 * MAT,
        WT_HI + 3 * MAT, WT_LO + 3 * MAT,
        WT_HI + 3 * MAT, WT_LO + 3 * MAT,
        bo, bo, bo, out, out, out);
}